// Round 3
// baseline (1257.045 us; speedup 1.0000x reference)
//
#include <hip/hip_runtime.h>
#include <stdint.h>

// Depthwise causal conv: y[b,c,p,q] = sum_{r<6,s<11} w[c,r,s]*xm[b,c,p+r-5,q+s-5]
// xm = x masked to lower triangle (h>=w); output masked to p>=q.
// N=2, C=16, H=W=2048.

#define HDIM 2048
#define WDIM 2048
#define CH   16
#define RTAP 6
#define STAP 11

#define TH 64     // sub-tile rows
#define TW 128    // sub-tile cols
#define LDSR 69   // TH + 5 top halo
#define NGRP 36   // 16B groups per row (8 left halo + 128 + 8 right)
#define NSLOT (LDSR * NGRP)  // 2484
#define NT 8      // sub-tiles per block (column segment of 512 rows)

typedef const __attribute__((address_space(1))) uint32_t* gptr_t;
typedef __attribute__((address_space(3))) uint32_t* lptr_t;

__global__ __launch_bounds__(256, 2)
void dwconv_causal(const float* __restrict__ x, const float* __restrict__ wgt,
                   float* __restrict__ out) {
  const int bx = blockIdx.x, seg = blockIdx.y, plane = blockIdx.z;
  const int q0 = bx * TW;
  const int tid = threadIdx.x;
  const size_t pb = (size_t)plane * HDIM * WDIM;
  const float* __restrict__ xp = x + pb;
  float* __restrict__ op = out + pb;

  __shared__ float lds[2][NSLOT * 4];  // 2 x 39744 B -> 2 blocks/CU

  // Weights are block-uniform -> scalar loads (SGPRs).
  const float* __restrict__ wc = wgt + (plane & (CH - 1)) * (RTAP * STAP);
  float wr[RTAP * STAP];
#pragma unroll
  for (int i = 0; i < RTAP * STAP; ++i) wr[i] = wc[i];

  const int tx = tid & 15, ty = tid >> 4;
  const int orow0 = ty * 4, ocol0 = tx * 8;

  // Stage sub-tile t into buffer b. Physical slot s holds row=s/36,
  // logical group g = (s%36) ^ ((row>>2)&1)  (bank swizzle; involution).
  // Async path requires hole-free contiguous active lanes (first-active-lane
  // base rule) -> pure tiles and __all(fullv) wave-instrs only.
  auto stage = [&](int t, int b) {
    const int p0 = (seg * NT + t) * TH;
    const bool pure = (bx > 0) && (q0 + 140 <= p0);  // all staged elems in-bounds+causal
    if (pure) {
#pragma unroll
      for (int j = 0; j < 10; ++j) {
        int slot = j * 256 + tid;
        if (slot < NSLOT) {  // prefix mask only -> lane0 active -> base OK
          int row = slot / NGRP;
          int gp = slot - row * NGRP;
          int g = gp ^ ((row >> 2) & 1);
          const float* ga = xp + (size_t)(p0 - 5 + row) * WDIM + (q0 - 8 + 4 * g);
          __builtin_amdgcn_global_load_lds((gptr_t)ga, (lptr_t)&lds[b][slot * 4],
                                           16, 0, 0);
        }
      }
    } else {
#pragma unroll
      for (int j = 0; j < 10; ++j) {
        int slot = j * 256 + tid;
        bool valid = slot < NSLOT;
        int row = valid ? slot / NGRP : 0;
        int gp = slot - row * NGRP;
        int g = gp ^ ((row >> 2) & 1);
        int ih = p0 - 5 + row;
        int cb = q0 - 8 + 4 * g;
        bool fullv = valid && (ih >= 0) && (cb >= 0) && (cb + 3 <= ih) &&
                     (cb + 3 < WDIM);
        if (__all(fullv)) {  // whole wave async, contiguous lanes
          const float* ga = xp + (size_t)ih * WDIM + cb;
          __builtin_amdgcn_global_load_lds((gptr_t)ga, (lptr_t)&lds[b][slot * 4],
                                           16, 0, 0);
        } else {             // reg roundtrip with full predication
          float4 v = make_float4(0.f, 0.f, 0.f, 0.f);
          if (valid && ih >= 0 && cb <= ih && cb + 3 >= 0 && cb < WDIM) {
            if (fullv) {
              v = *(const float4*)(xp + (size_t)ih * WDIM + cb);
            } else {
              float* vv = &v.x;
#pragma unroll
              for (int e = 0; e < 4; ++e) {
                int iw = cb + e;
                if (iw >= 0 && iw < WDIM && iw <= ih)
                  vv[e] = xp[(size_t)ih * WDIM + iw];
              }
            }
          }
          if (valid) *(float4*)&lds[b][slot * 4] = v;
        }
      }
    }
  };

  // Prologue: stage tile 0 if it computes.
  {
    const int p0 = seg * NT * TH;
    if (p0 + TH - 1 >= q0) stage(0, 0);
  }

#pragma unroll 1
  for (int t = 0; t < NT; ++t) {
    // Tile t's loads were issued last iteration (or prologue): one full
    // compute phase of latency hiding. Drain, then sync buffers.
    asm volatile("s_waitcnt vmcnt(0) lgkmcnt(0)" ::: "memory");
    __builtin_amdgcn_s_barrier();
    __builtin_amdgcn_sched_barrier(0);

    const int p0 = (seg * NT + t) * TH;
    // Prefetch next sub-tile into the other buffer (overlaps compute below).
    if (t + 1 < NT) {
      const int p0n = p0 + TH;
      if (p0n + TH - 1 >= q0) stage(t + 1, (t + 1) & 1);
    }

    const int qb = q0 + ocol0;
    if (p0 + TH - 1 >= q0) {
      // ---- compute 4x8 per thread from lds[t&1] ----
      const float* __restrict__ lb = &lds[t & 1][0];
      float acc[4][8];
#pragma unroll
      for (int a = 0; a < 4; ++a)
#pragma unroll
        for (int b2 = 0; b2 < 8; ++b2) acc[a][b2] = 0.f;

#pragma unroll
      for (int ihl = 0; ihl < 9; ++ihl) {
        const int l = orow0 + ihl;
        const int xr = (l >> 2) & 1;
        float xrow[24];
#pragma unroll
        for (int k = 0; k < 6; ++k) {
          int gs = (tx * 2 + k) ^ xr;
          *(float4*)&xrow[4 * k] = *(const float4*)&lb[(l * NGRP + gs) * 4];
        }
#pragma unroll
        for (int ro = 0; ro < 4; ++ro) {
          if (ro < ihl - 5 || ro > ihl) continue;  // const after unroll
          const int rr = ihl - ro;
#pragma unroll
          for (int s = 0; s < STAP; ++s) {
            const float wv = wr[rr * STAP + s];
#pragma unroll
            for (int cc = 0; cc < 8; ++cc)
              acc[ro][cc] += wv * xrow[cc + s + 3];  // window [3,20]
          }
        }
      }

      const bool fullcausal = (q0 + TW - 1 <= p0);  // mask provably no-op
#pragma unroll
      for (int ro = 0; ro < 4; ++ro) {
        const int p = p0 + orow0 + ro;
        if (!fullcausal) {
#pragma unroll
          for (int cc = 0; cc < 8; ++cc)
            if (qb + cc > p) acc[ro][cc] = 0.f;
        }
        *(float4*)(op + (size_t)p * WDIM + qb) =
            make_float4(acc[ro][0], acc[ro][1], acc[ro][2], acc[ro][3]);
        *(float4*)(op + (size_t)p * WDIM + qb + 4) =
            make_float4(acc[ro][4], acc[ro][5], acc[ro][6], acc[ro][7]);
      }
    } else {
      // strictly-upper sub-tile: zeros
      const float4 z = make_float4(0.f, 0.f, 0.f, 0.f);
#pragma unroll
      for (int ro = 0; ro < 4; ++ro) {
        const int p = p0 + orow0 + ro;
        *(float4*)(op + (size_t)p * WDIM + qb) = z;
        *(float4*)(op + (size_t)p * WDIM + qb + 4) = z;
      }
    }
  }
}

extern "C" void kernel_launch(void* const* d_in, const int* in_sizes, int n_in,
                              void* d_out, int out_size, void* d_ws, size_t ws_size,
                              hipStream_t stream) {
  const float* x   = (const float*)d_in[0];
  const float* wgt = (const float*)d_in[1];
  float* out       = (float*)d_out;
  dim3 grid(WDIM / TW, HDIM / (TH * NT), 2 * CH);  // (16, 4, 32)
  dwconv_causal<<<grid, dim3(256), 0, stream>>>(x, wgt, out);
}